// Round 7
// baseline (214.824 us; speedup 1.0000x reference)
//
#include <hip/hip_runtime.h>
#include <stdint.h>

#define SS 64
#define NN 4096
#define FF 32
#define HH 64
#define OO 2
#define G3 192

typedef float f32x4 __attribute__((ext_vector_type(4)));
typedef short bf16x8 __attribute__((ext_vector_type(8)));
typedef unsigned short u16x8 __attribute__((ext_vector_type(8)));

#define AS1 __attribute__((address_space(1)))
#define AS3 __attribute__((address_space(3)))

__device__ __forceinline__ unsigned short f2bf(float f) {
  union { float f; uint32_t u; } v; v.f = f;
  uint32_t u = v.u;
  uint32_t r = (u + 0x7FFFu + ((u >> 16) & 1u)) >> 16;
  return (unsigned short)r;
}
__device__ __forceinline__ float bf2f(unsigned short s) {
  union { uint32_t u; float f; } v; v.u = ((uint32_t)s) << 16;
  return v.f;
}

// ---------------- prep: adj f32->bf16 + rowsum (blocks 0..4095, 1 row each)
// ----------------       x transpose -> Xt[s*32+f][j] bf16 (blocks 4096..8191)
__global__ __launch_bounds__(256) void k_prep(const float* __restrict__ adj,
                                              unsigned short* __restrict__ adjb,
                                              float* __restrict__ rowsum,
                                              const float* __restrict__ x,
                                              unsigned short* __restrict__ Xt) {
  __shared__ float xl[64][33];
  __shared__ float ps[4];
  int tid = threadIdx.x;
  if (blockIdx.x < 4096) {
    int row = blockIdx.x;
    const float4* src = (const float4*)(adj + (size_t)row * 4096);
    ushort4* dst = (ushort4*)(adjb + (size_t)row * 4096);
    float sum = 0.f;
    #pragma unroll
    for (int q = 0; q < 4; ++q) {
      int idx = q * 256 + tid;
      float4 v = src[idx];
      ushort4 r;
      r.x = f2bf(v.x); r.y = f2bf(v.y); r.z = f2bf(v.z); r.w = f2bf(v.w);
      dst[idx] = r;
      sum += (v.x + v.y) + (v.z + v.w);
    }
    #pragma unroll
    for (int off = 1; off < 64; off <<= 1) sum += __shfl_xor(sum, off);
    if ((tid & 63) == 0) ps[tid >> 6] = sum;
    __syncthreads();
    if (tid == 0) rowsum[row] = (ps[0] + ps[1]) + (ps[2] + ps[3]);
    return;
  }
  int bs = blockIdx.x - 4096;
  int s = bs >> 6, jb = (bs & 63) << 6;
  const float4* xg = (const float4*)(x + ((size_t)s * NN + jb) * FF);
  #pragma unroll
  for (int ii = 0; ii < 2; ++ii) {
    int idx = tid + ii * 256;
    float4 v = xg[idx];
    int j = idx >> 3, f = (idx & 7) << 2;
    xl[j][f] = v.x; xl[j][f + 1] = v.y; xl[j][f + 2] = v.z; xl[j][f + 3] = v.w;
  }
  __syncthreads();
  int f = tid >> 3, jc = tid & 7;
  u16x8 ov;
  #pragma unroll
  for (int jj = 0; jj < 8; ++jj) ov[jj] = (short)f2bf(xl[jc * 8 + jj][f]);
  *(u16x8*)(Xt + (size_t)(s * 32 + f) * 4096 + jb + jc * 8) = ov;
}

// =====================================================================
// GEMM-AX fused: C1 = adj @ Xt^T (in acc), then in-block GCN layer-1+2:
// h = relu(C1@W1 + rowsum*b1); B2t = h@W2 + b2.
// 128x256 tile, BK=64, 8 waves, TRIPLE-buffered LDS, register ping-pong
// fragments: MFMA fires at K-tile top from preloaded regs; next tile's
// 16 ds_reads issue under the MFMA shadow; counted vmcnt(6), lgkm0 fence
// before the barrier closes the deferred-read-vs-overwrite race.
// =====================================================================
#define SBAR()   asm volatile("s_barrier" ::: "memory")
#define VMCNT6() asm volatile("s_waitcnt vmcnt(6)" ::: "memory")
#define VMCNT0() asm volatile("s_waitcnt vmcnt(0)" ::: "memory")
#define VMLG()   asm volatile("s_waitcnt vmcnt(6) lgkmcnt(0)" ::: "memory")

__global__ __launch_bounds__(512, 2) void k_gemmAX(
    const unsigned short* __restrict__ A,
    const unsigned short* __restrict__ B,
    const float* __restrict__ rowsum,
    const float* __restrict__ W1f,
    const float* __restrict__ b1f,
    const float* __restrict__ W2f,
    const float* __restrict__ b2f,
    unsigned short* __restrict__ B2t) {
  __shared__ __align__(16) char lds[147456];
  __shared__ float w1l[2048];
  __shared__ float w2l[128];
  __shared__ float b1l[64];
  __shared__ float b2l[2];
  const int tid = threadIdx.x;
  const int wid = tid >> 6, l = tid & 63;
  const int wr2 = wid >> 2, wc2 = wid & 3;

  // stage small weights (drained by the first __syncthreads)
  *(float4*)&w1l[tid * 4] = ((const float4*)W1f)[tid];
  if (tid < 32) *(float4*)&w2l[tid * 4] = ((const float4*)W2f)[tid];
  if (tid < 16) *(float4*)&b1l[tid * 4] = ((const float4*)b1f)[tid];
  if (tid < 2) b2l[tid] = b2f[tid];
  __syncthreads();

  int bid = blockIdx.x;
  int swz = (bid & 7) * 32 + (bid >> 3);   // bijective XCD swizzle (256 = 8*32)
  const int i0 = (swz >> 3) * 128;         // 32 i-tiles
  const int c0 = (swz & 7) * 256;          // 8 sf-tiles

  const int aOffC = wr2 * 8192 + (l & 15) * 128;
  const int bOffC = 16384 + wc2 * 8192 + (l & 15) * 128;
  const int colKK0 = (((l >> 4) * 16)) ^ ((l & 7) << 4);
  const int colKK1 = ((64 + (l >> 4) * 16)) ^ ((l & 7) << 4);

  const int srow = tid >> 3;
  const int scol = (((tid & 7) ^ (srow & 7)) << 4);
  const char* gA = (const char*)A + (size_t)(i0 + srow) * 8192 + scol;
  const char* gB = (const char*)B + (size_t)(c0 + srow) * 8192 + scol;
  char* ldsW = (char*)lds + wid * 1024;
  const char* ldsR = (const char*)lds;

  f32x4 acc[4][4];
  #pragma unroll
  for (int m = 0; m < 4; ++m)
    #pragma unroll
    for (int n = 0; n < 4; ++n) acc[m][n] = {0.f, 0.f, 0.f, 0.f};

  bf16x8 afA[4][2], bfA[4][2], afB[4][2], bfB[4][2];

#define STAGE6(K2, BOFS) do {                                                        \
    __builtin_amdgcn_global_load_lds((const AS1 void*)(gA + (K2)),                   \
        (AS3 void*)(ldsW + (BOFS)), 16, 0, 0);                                       \
    __builtin_amdgcn_global_load_lds((const AS1 void*)(gA + 524288 + (K2)),          \
        (AS3 void*)(ldsW + (BOFS) + 8192), 16, 0, 0);                                \
    __builtin_amdgcn_global_load_lds((const AS1 void*)(gB + (K2)),                   \
        (AS3 void*)(ldsW + (BOFS) + 16384), 16, 0, 0);                               \
    __builtin_amdgcn_global_load_lds((const AS1 void*)(gB + 524288 + (K2)),          \
        (AS3 void*)(ldsW + (BOFS) + 24576), 16, 0, 0);                               \
    __builtin_amdgcn_global_load_lds((const AS1 void*)(gB + 1048576 + (K2)),         \
        (AS3 void*)(ldsW + (BOFS) + 32768), 16, 0, 0);                               \
    __builtin_amdgcn_global_load_lds((const AS1 void*)(gB + 1572864 + (K2)),         \
        (AS3 void*)(ldsW + (BOFS) + 40960), 16, 0, 0);                               \
  } while (0)

#define READ_SET(AF, BF, BOFS) do {                                                  \
    _Pragma("unroll")                                                                \
    for (int _m = 0; _m < 4; ++_m) {                                                 \
      const char* _p = ldsR + (BOFS) + aOffC + _m * 2048;                            \
      AF[_m][0] = *(const bf16x8*)(_p + colKK0);                                     \
      AF[_m][1] = *(const bf16x8*)(_p + colKK1);                                     \
    }                                                                                \
    _Pragma("unroll")                                                                \
    for (int _n = 0; _n < 4; ++_n) {                                                 \
      const char* _q = ldsR + (BOFS) + bOffC + _n * 2048;                            \
      BF[_n][0] = *(const bf16x8*)(_q + colKK0);                                     \
      BF[_n][1] = *(const bf16x8*)(_q + colKK1);                                     \
    } } while (0)

#define MFMA_NH(AF, BF, N0) do {                                                     \
    __builtin_amdgcn_s_setprio(1);                                                   \
    _Pragma("unroll")                                                                \
    for (int _kk = 0; _kk < 2; ++_kk)                                                \
      _Pragma("unroll")                                                              \
      for (int _m = 0; _m < 4; ++_m)                                                 \
        _Pragma("unroll")                                                            \
        for (int _j = 0; _j < 2; ++_j)                                               \
          acc[_m][(N0) + _j] = __builtin_amdgcn_mfma_f32_16x16x32_bf16(              \
              AF[_m][_kk], BF[(N0) + _j][_kk], acc[_m][(N0) + _j], 0, 0, 0);         \
    __builtin_amdgcn_s_setprio(0);                                                   \
  } while (0)

  // Prologue: t0->buf0, t1->buf1; certify t0; preload frags(t0); t2->buf2;
  // certify t1 + frag delivery; barrier.
  STAGE6(0, 0);
  STAGE6(128, 49152);
  VMCNT6();
  SBAR();
  READ_SET(afA, bfA, 0);
  STAGE6(256, 98304);
  VMLG();
  SBAR();

  int bCur = 0, bNext = 49152;
  for (int it = 0; it < 32; ++it) {
    const int kt = it * 2;
    {  // body A: even kt, frags in afA/bfA
      const int k2 = ((kt + 3) & 63) * 128;
      STAGE6(k2, bCur);                 // overwrites cur buf (frags already in regs)
      MFMA_NH(afA, bfA, 0);
      READ_SET(afB, bfB, bNext);        // next tile's frags, under MFMA shadow
      MFMA_NH(afA, bfA, 2);
      VMLG();                           // certify tile kt+2; own ds_reads delivered
      SBAR();
      bCur = bNext; bNext = (bNext == 98304) ? 0 : bNext + 49152;
    }
    {  // body B: odd kt, frags in afB/bfB
      const int k2 = ((kt + 4) & 63) * 128;
      STAGE6(k2, bCur);
      MFMA_NH(afB, bfB, 0);
      READ_SET(afA, bfA, bNext);
      MFMA_NH(afB, bfB, 2);
      VMLG();
      SBAR();
      bCur = bNext; bNext = (bNext == 98304) ? 0 : bNext + 49152;
    }
  }
  VMCNT0();
  __syncthreads();   // LDS now reusable

  // ---- fused GCN output epilogue ----
  // acc -> C1 tile bf16 in LDS, [128 rows][264 u16] (528B stride kills
  // the power-of-2 read conflict), then per-thread 2 (s, i) pairs run the
  // verified gcn1out math; write B2t directly.
  unsigned short* C1L = (unsigned short*)lds;
  {
    const int rb = wr2 * 64 + (l >> 4) * 4;
    const int cbL = wc2 * 64 + (l & 15);
    #pragma unroll
    for (int m = 0; m < 4; ++m)
      #pragma unroll
      for (int r = 0; r < 4; ++r) {
        const int row = rb + m * 16 + r;
        #pragma unroll
        for (int n = 0; n < 4; ++n)
          C1L[row * 264 + cbL + n * 16] = f2bf(acc[m][n][r]);
      }
  }
  __syncthreads();
  #pragma unroll
  for (int pp = 0; pp < 2; ++pp) {
    const int p = tid + pp * 512;
    const int s = p >> 7, il = p & 127;
    const u16x8* cp = (const u16x8*)(C1L + il * 264 + s * 32);
    float cf[32];
    #pragma unroll
    for (int q = 0; q < 4; ++q) {
      u16x8 v = cp[q];
      #pragma unroll
      for (int e = 0; e < 8; ++e) cf[q * 8 + e] = bf2f((unsigned short)v[e]);
    }
    const float rs = rowsum[i0 + il];
    const f32x4* b1v = (const f32x4*)b1l;
    f32x4 h[16];
    #pragma unroll
    for (int t = 0; t < 16; ++t) h[t] = rs * b1v[t];
    #pragma unroll
    for (int f = 0; f < 32; ++f) {
      const float c = cf[f];
      const f32x4* wrow = (const f32x4*)(w1l + f * 64);
      #pragma unroll
      for (int t = 0; t < 16; ++t) h[t] += c * wrow[t];
    }
    float o0 = b2l[0], o1 = b2l[1];
    #pragma unroll
    for (int t = 0; t < 16; ++t)
      #pragma unroll
      for (int e = 0; e < 4; ++e) {
        float a = h[t][e];
        a = a > 0.f ? a : 0.f;
        o0 += a * w2l[(t * 4 + e) * 2];
        o1 += a * w2l[(t * 4 + e) * 2 + 1];
      }
    B2t[(size_t)(((c0 >> 5) + s) * 2 + 0) * 4096 + i0 + il] = f2bf(o0);
    B2t[(size_t)(((c0 >> 5) + s) * 2 + 1) * 4096 + i0 + il] = f2bf(o1);
  }
}

// ---------------- shared MFMA GEMM core (m97-style, used by gemm2) ----------------
__device__ __forceinline__ void gemm_core(const unsigned short* __restrict__ A,
                                          const unsigned short* __restrict__ B,
                                          int i0, int c0, int k0base, int ksteps,
                                          f32x4 acc[4][4],
                                          unsigned short* Als, unsigned short* Bls) {
  const int tid = threadIdx.x;
  const int w = tid >> 6, l = tid & 63;
  const int srow = (l >> 2);
  const int scol = (l & 3) * 16;
  for (int kt = 0; kt < ksteps; ++kt) {
    int k0 = k0base + kt * 32;
    #pragma unroll
    for (int q = 0; q < 2; ++q) {
      int r = w * 32 + q * 16 + srow;
      const char* ga = (const char*)(A + (size_t)(i0 + r) * 4096 + k0) + scol;
      __builtin_amdgcn_global_load_lds(
          (const AS1 void*)ga,
          (AS3 void*)((char*)Als + w * 2048 + q * 1024), 16, 0, 0);
      const char* gb = (const char*)(B + (size_t)(c0 + r) * 4096 + k0) + scol;
      __builtin_amdgcn_global_load_lds(
          (const AS1 void*)gb,
          (AS3 void*)((char*)Bls + w * 2048 + q * 1024), 16, 0, 0);
    }
    __syncthreads();
    const int wr = w >> 1, wc = w & 1;
    bf16x8 af[4], bff[4];
    #pragma unroll
    for (int m = 0; m < 4; ++m)
      af[m] = *(const bf16x8*)(Als + (wr * 64 + m * 16 + (l & 15)) * 32 + (l >> 4) * 8);
    #pragma unroll
    for (int n = 0; n < 4; ++n)
      bff[n] = *(const bf16x8*)(Bls + (wc * 64 + n * 16 + (l & 15)) * 32 + (l >> 4) * 8);
    #pragma unroll
    for (int m = 0; m < 4; ++m)
      #pragma unroll
      for (int n = 0; n < 4; ++n)
        acc[m][n] = __builtin_amdgcn_mfma_f32_16x16x32_bf16(af[m], bff[n], acc[m][n], 0, 0, 0);
    __syncthreads();
  }
}

// ---------------- GEMM2 split-K: Gp[ks][i][c2] partial f32 ----------------
__global__ __launch_bounds__(256) void k_gemm2(const unsigned short* __restrict__ A,
                                               const unsigned short* __restrict__ B,
                                               float* __restrict__ Gp) {
  __shared__ unsigned short Als[128 * 32], Bls[128 * 32];
  int id = blockIdx.x;
  int bi = id & 31, ks = id >> 5;
  int i0 = bi * 128;
  f32x4 acc[4][4];
  #pragma unroll
  for (int m = 0; m < 4; ++m)
    #pragma unroll
    for (int n = 0; n < 4; ++n) acc[m][n] = {0.f, 0.f, 0.f, 0.f};
  gemm_core(A, B, i0, 0, ks * 512, 16, acc, Als, Bls);
  float* outp = Gp + (size_t)ks * 4096 * 128;
  int l = threadIdx.x & 63, w = threadIdx.x >> 6;
  int wr = w >> 1, wc = w & 1;
  int rbase = i0 + wr * 64 + (l >> 4) * 4;
  int cbase = wc * 64 + (l & 15);
  #pragma unroll
  for (int m = 0; m < 4; ++m)
    #pragma unroll
    for (int n = 0; n < 4; ++n)
      #pragma unroll
      for (int r = 0; r < 4; ++r)
        outp[(size_t)(rbase + m * 16 + r) * 128 + cbase + n * 16] = acc[m][n][r];
}

// ---------------- reduce split-K + log_softmax -> R[s][i*2+o] f32 ----------------
__global__ __launch_bounds__(256) void k_lsm(const float* __restrict__ Gp,
                                             float* __restrict__ Rm) {
  __shared__ float Gacc[32][130];
  int i0 = blockIdx.x * 32;
  int tid = threadIdx.x;
  float4 v[4];
  #pragma unroll
  for (int i = 0; i < 4; ++i) v[i] = {0.f, 0.f, 0.f, 0.f};
  for (int ks = 0; ks < 8; ++ks) {
    const float4* gp4 = ((const float4*)Gp) + (size_t)ks * 131072 + (size_t)i0 * 32;
    #pragma unroll
    for (int i = 0; i < 4; ++i) {
      float4 t = gp4[tid + i * 256];
      v[i].x += t.x; v[i].y += t.y; v[i].z += t.z; v[i].w += t.w;
    }
  }
  #pragma unroll
  for (int i = 0; i < 4; ++i) {
    int f4i = tid + i * 256, row = f4i >> 5, c = (f4i & 31) * 4;
    Gacc[row][c] = v[i].x; Gacc[row][c + 1] = v[i].y;
    Gacc[row][c + 2] = v[i].z; Gacc[row][c + 3] = v[i].w;
  }
  __syncthreads();
  #pragma unroll
  for (int j = 0; j < 8; ++j) {
    int p = j * 256 + tid;
    int ii = p & 31, s = p >> 5;
    float g0 = Gacc[ii][s * 2], g1 = Gacc[ii][s * 2 + 1];
    float m = fmaxf(g0, g1);
    float lse = m + logf(expf(g0 - m) + expf(g1 - m));
    float2 o_; o_.x = g0 - lse; o_.y = g1 - lse;
    *((float2*)(Rm + (size_t)s * 8192 + (size_t)(i0 + ii) * 2)) = o_;
  }
}

// ---------------- gi0 partial: part[ks][t][g] = R[t] . Wih0[g] over c-range ----------------
__global__ __launch_bounds__(256) void k_gi0(const float* __restrict__ Rm,
                                             const float* __restrict__ Wih0,
                                             float* __restrict__ part) {
  __shared__ float4 Wl[4 * 128];
  int gb = blockIdx.x % 48, ks = blockIdx.x / 48;
  int c0 = ks * 512;
  int tid = threadIdx.x;
  #pragma unroll
  for (int i = 0; i < 2; ++i) {
    int idx = tid + i * 256;
    int g = idx >> 7, c4 = idx & 127;
    Wl[g * 128 + c4] = ((const float4*)(Wih0 + (size_t)(gb * 4 + g) * 8192 + c0))[c4];
  }
  __syncthreads();
  int w = tid >> 6, lane = tid & 63;
  for (int pass = 0; pass < 16; ++pass) {
    int t = pass * 4 + w;
    float a0 = 0.f, a1 = 0.f, a2 = 0.f, a3 = 0.f;
    const float4* rg = (const float4*)(Rm + (size_t)t * 8192 + c0);
    #pragma unroll
    for (int i = 0; i < 2; ++i) {
      int c4 = i * 64 + lane;
      float4 r4 = rg[c4];
      float4 w0 = Wl[c4], w1 = Wl[128 + c4], w2 = Wl[256 + c4], w3 = Wl[384 + c4];
      a0 += r4.x * w0.x + r4.y * w0.y + r4.z * w0.z + r4.w * w0.w;
      a1 += r4.x * w1.x + r4.y * w1.y + r4.z * w1.z + r4.w * w1.w;
      a2 += r4.x * w2.x + r4.y * w2.y + r4.z * w2.z + r4.w * w2.w;
      a3 += r4.x * w3.x + r4.y * w3.y + r4.z * w3.z + r4.w * w3.w;
    }
    #pragma unroll
    for (int off = 1; off < 64; off <<= 1) {
      a0 += __shfl_xor(a0, off);
      a1 += __shfl_xor(a1, off);
      a2 += __shfl_xor(a2, off);
      a3 += __shfl_xor(a3, off);
    }
    if (lane == 0) {
      float4 o_; o_.x = a0; o_.y = a1; o_.z = a2; o_.w = a3;
      *((float4*)(part + ((size_t)ks * 64 + t) * 192 + gb * 4)) = o_;
    }
  }
}

__global__ __launch_bounds__(256) void k_gi0red(const float* __restrict__ part,
                                                const float* __restrict__ bih0,
                                                float* __restrict__ gi0) {
  int idx = blockIdx.x * 256 + threadIdx.x;
  if (idx < 12288) {
    float s_ = bih0[idx % 192];
    for (int ks = 0; ks < 16; ++ks) s_ += part[ks * 12288 + idx];
    gi0[idx] = s_;
  }
}

// =====================================================================
// MFMA GRU (unchanged from round 6)
// =====================================================================
__device__ __forceinline__ float fsigm(float x) {
  return __builtin_amdgcn_rcpf(1.f + __expf(-x));
}
__device__ __forceinline__ float ftanh(float x) {
  return 1.f - 2.f * __builtin_amdgcn_rcpf(1.f + __expf(2.f * x));
}

__global__ __launch_bounds__(384) void k_gru(const float* __restrict__ gi0,
                                             const float* __restrict__ Whh0,
                                             const float* __restrict__ bhh0,
                                             const float* __restrict__ Wih1,
                                             const float* __restrict__ Whh1,
                                             const float* __restrict__ bih1,
                                             const float* __restrict__ bhh1,
                                             float* __restrict__ out) {
  __shared__ float gil[64][192];
  __shared__ float gout[576];
  __shared__ __align__(16) unsigned short hv[2][64];
  const int tid = threadIdx.x;
  const int w = tid >> 6, l = tid & 63;
  const int matw = w >> 1, half = w & 1;
  const float* Wm = (matw == 0) ? Whh0 : (matw == 1 ? Wih1 : Whh1);
  const int mi = (matw == 2) ? 1 : 0;

  bf16x8 afr[6][2];
  #pragma unroll
  for (int rbi = 0; rbi < 6; ++rbi) {
    int g = (half * 6 + rbi) * 16 + (l & 15);
    #pragma unroll
    for (int kh = 0; kh < 2; ++kh) {
      int k0 = kh * 32 + (l >> 4) * 8;
      const float4* src = (const float4*)(Wm + (size_t)g * 64 + k0);
      float4 v0 = src[0], v1 = src[1];
      bf16x8 a;
      a[0] = (short)f2bf(v0.x); a[1] = (short)f2bf(v0.y);
      a[2] = (short)f2bf(v0.z); a[3] = (short)f2bf(v0.w);
      a[4] = (short)f2bf(v1.x); a[5] = (short)f2bf(v1.y);
      a[6] = (short)f2bf(v1.z); a[7] = (short)f2bf(v1.w);
      afr[rbi][kh] = a;
    }
  }
  {
    float4* gf = (float4*)&gil[0][0];
    const float4* gs = (const float4*)gi0;
    #pragma unroll
    for (int i = 0; i < 8; ++i) gf[i * 384 + tid] = gs[i * 384 + tid];
  }
  if (tid < 128) hv[tid >> 6][tid & 63] = 0;

  float hreg = 0.f;
  float bR = 0.f, bZ = 0.f, bNa = 0.f, bNb = 0.f;
  if (tid < 64) {
    bR = bhh0[tid]; bZ = bhh0[64 + tid]; bNa = bhh0[128 + tid];
  } else if (tid < 128) {
    int g = tid - 64;
    bR = bih1[g] + bhh1[g];
    bZ = bih1[64 + g] + bhh1[64 + g];
    bNa = bih1[128 + g];
    bNb = bhh1[128 + g];
  }
  asm volatile("s_waitcnt lgkmcnt(0)\n\ts_barrier" ::: "memory");

  const int gwb = matw * 192 + half * 96 + (l >> 4) * 4;
  const f32x4 zacc = {0.f, 0.f, 0.f, 0.f};

  for (int i = 0; i <= 64; ++i) {
    bf16x8 b0 = *(const bf16x8*)&hv[mi][(l >> 4) * 8];
    bf16x8 b1 = *(const bf16x8*)&hv[mi][32 + (l >> 4) * 8];
    #pragma unroll
    for (int rbi = 0; rbi < 6; ++rbi) {
      f32x4 a_ = __builtin_amdgcn_mfma_f32_16x16x32_bf16(afr[rbi][0], b0, zacc, 0, 0, 0);
      a_ = __builtin_amdgcn_mfma_f32_16x16x32_bf16(afr[rbi][1], b1, a_, 0, 0, 0);
      if (!(l & 15)) *(f32x4*)&gout[gwb + rbi * 16] = a_;
    }
    asm volatile("s_waitcnt lgkmcnt(0)\n\ts_barrier" ::: "memory");
    if (tid < 64) {
      if (i < 64) {
        float r = fsigm(gil[i][tid] + gout[tid] + bR);
        float z = fsigm(gil[i][64 + tid] + gout[64 + tid] + bZ);
        float n = ftanh(gil[i][128 + tid] + r * (gout[128 + tid] + bNa));
        hreg = (1.f - z) * n + z * hreg;
        hv[0][tid] = f2bf(hreg);
      }
    } else if (tid < 128 && i > 0) {
      int g = tid - 64;
      float r = fsigm(gout[192 + g] + gout[384 + g] + bR);
      float z = fsigm(gout[256 + g] + gout[448 + g] + bZ);
      float n = ftanh((gout[320 + g] + bNa) + r * (gout[512 + g] + bNb));
      hreg = (1.f - z) * n + z * hreg;
      hv[1][g] = f2bf(hreg);
      out[(i - 1) * 64 + g] = hreg;
    }
    asm volatile("s_waitcnt lgkmcnt(0)\n\ts_barrier" ::: "memory");
  }
  if (tid < 64) out[4096 + tid] = hreg;
  else if (tid < 128) out[4096 + 64 + (tid - 64)] = hreg;
}

extern "C" void kernel_launch(void* const* d_in, const int* in_sizes, int n_in,
                              void* d_out, int out_size, void* d_ws, size_t ws_size,
                              hipStream_t stream) {
  const float* x    = (const float*)d_in[0];
  const float* adj  = (const float*)d_in[1];
  const float* W1   = (const float*)d_in[2];
  const float* b1   = (const float*)d_in[3];
  const float* W2   = (const float*)d_in[4];
  const float* b2   = (const float*)d_in[5];
  const float* Wih0 = (const float*)d_in[6];
  const float* Whh0 = (const float*)d_in[7];
  const float* bih0 = (const float*)d_in[8];
  const float* bhh0 = (const float*)d_in[9];
  const float* Wih1 = (const float*)d_in[10];
  const float* Whh1 = (const float*)d_in[11];
  const float* bih1 = (const float*)d_in[12];
  const float* bhh1 = (const float*)d_in[13];
  float* out = (float*)d_out;

  char* ws = (char*)d_ws;
  unsigned short* adjb = (unsigned short*)ws;                      // 33.55MB
  unsigned short* Xt   = (unsigned short*)(ws + 33554432);         // 16.78MB
  float* rowsum        = (float*)(ws + 67108864);                  // 16KB
  float* Gp            = (float*)(ws + 67125248);                  // 16.78MB
  float* Rm            = (float*)(ws + 83902464);                  // 2MB
  float* part          = (float*)(ws + 85999616);                  // 768KB
  float* gi0           = (float*)(ws + 86786048);                  // 48KB
  unsigned short* B2t  = (unsigned short*)(ws + 86835200);         // 1MB

  k_prep<<<8192, 256, 0, stream>>>(adj, adjb, rowsum, x, Xt);
  k_gemmAX<<<256, 512, 0, stream>>>(adjb, Xt, rowsum, W1, b1, W2, b2, B2t);
  k_gemm2<<<256, 256, 0, stream>>>(adjb, B2t, Gp);
  k_lsm<<<128, 256, 0, stream>>>(Gp, Rm);
  k_gi0<<<768, 256, 0, stream>>>(Rm, Wih0, part);
  k_gi0red<<<48, 256, 0, stream>>>(part, bih0, gi0);
  k_gru<<<1, 384, 0, stream>>>(gi0, Whh0, bhh0, Wih1, Whh1, bih1, bhh1, out);
}

// Round 8
// 213.809 us; speedup vs baseline: 1.0047x; 1.0047x over previous
//
#include <hip/hip_runtime.h>
#include <stdint.h>

#define SS 64
#define NN 4096
#define FF 32
#define HH 64
#define OO 2
#define G3 192

typedef float f32x4 __attribute__((ext_vector_type(4)));
typedef short bf16x8 __attribute__((ext_vector_type(8)));
typedef unsigned short u16x8 __attribute__((ext_vector_type(8)));

#define AS1 __attribute__((address_space(1)))
#define AS3 __attribute__((address_space(3)))

__device__ __forceinline__ unsigned short f2bf(float f) {
  union { float f; uint32_t u; } v; v.f = f;
  uint32_t u = v.u;
  uint32_t r = (u + 0x7FFFu + ((u >> 16) & 1u)) >> 16;
  return (unsigned short)r;
}
__device__ __forceinline__ float bf2f(unsigned short s) {
  union { uint32_t u; float f; } v; v.u = ((uint32_t)s) << 16;
  return v.f;
}

// ---------------- prep: adj f32->bf16 + rowsum (blocks 0..4095, 1 row each)
// ----------------       x transpose -> Xt[s*32+f][j] bf16 (blocks 4096..8191)
__global__ __launch_bounds__(256) void k_prep(const float* __restrict__ adj,
                                              unsigned short* __restrict__ adjb,
                                              float* __restrict__ rowsum,
                                              const float* __restrict__ x,
                                              unsigned short* __restrict__ Xt) {
  __shared__ float xl[64][33];
  __shared__ float ps[4];
  int tid = threadIdx.x;
  if (blockIdx.x < 4096) {
    int row = blockIdx.x;
    const float4* src = (const float4*)(adj + (size_t)row * 4096);
    ushort4* dst = (ushort4*)(adjb + (size_t)row * 4096);
    float sum = 0.f;
    #pragma unroll
    for (int q = 0; q < 4; ++q) {
      int idx = q * 256 + tid;
      float4 v = src[idx];
      ushort4 r;
      r.x = f2bf(v.x); r.y = f2bf(v.y); r.z = f2bf(v.z); r.w = f2bf(v.w);
      dst[idx] = r;
      sum += (v.x + v.y) + (v.z + v.w);
    }
    #pragma unroll
    for (int off = 1; off < 64; off <<= 1) sum += __shfl_xor(sum, off);
    if ((tid & 63) == 0) ps[tid >> 6] = sum;
    __syncthreads();
    if (tid == 0) rowsum[row] = (ps[0] + ps[1]) + (ps[2] + ps[3]);
    return;
  }
  int bs = blockIdx.x - 4096;
  int s = bs >> 6, jb = (bs & 63) << 6;
  const float4* xg = (const float4*)(x + ((size_t)s * NN + jb) * FF);
  #pragma unroll
  for (int ii = 0; ii < 2; ++ii) {
    int idx = tid + ii * 256;
    float4 v = xg[idx];
    int j = idx >> 3, f = (idx & 7) << 2;
    xl[j][f] = v.x; xl[j][f + 1] = v.y; xl[j][f + 2] = v.z; xl[j][f + 3] = v.w;
  }
  __syncthreads();
  int f = tid >> 3, jc = tid & 7;
  u16x8 ov;
  #pragma unroll
  for (int jj = 0; jj < 8; ++jj) ov[jj] = (short)f2bf(xl[jc * 8 + jj][f]);
  *(u16x8*)(Xt + (size_t)(s * 32 + f) * 4096 + jb + jc * 8) = ov;
}

// =====================================================================
// GEMM-AX fused: C1 = adj @ Xt^T (in acc) with the ROUND-6 proven K-loop
// (single frag set, triple-buffered LDS, vmcnt(6), 1 barrier/K-tile),
// then in-block GCN layers: h = relu(C1@W1 + rowsum*b1); B2t = h@W2+b2.
// =====================================================================
#define SBAR()   asm volatile("s_barrier" ::: "memory")
#define VMCNT6() asm volatile("s_waitcnt vmcnt(6)" ::: "memory")
#define VMCNT0() asm volatile("s_waitcnt vmcnt(0)" ::: "memory")

__global__ __launch_bounds__(512, 2) void k_gemmAX(
    const unsigned short* __restrict__ A,
    const unsigned short* __restrict__ B,
    const float* __restrict__ rowsum,
    const float* __restrict__ W1f,
    const float* __restrict__ b1f,
    const float* __restrict__ W2f,
    const float* __restrict__ b2f,
    unsigned short* __restrict__ B2t) {
  __shared__ __align__(16) char lds[147456];
  __shared__ float w1l[2048];
  __shared__ float w2l[128];
  __shared__ float b1l[64];
  __shared__ float b2l[2];
  const int tid = threadIdx.x;
  const int wid = tid >> 6, l = tid & 63;
  const int wr2 = wid >> 2, wc2 = wid & 3;

  // stage small weights (drained by the first __syncthreads)
  *(float4*)&w1l[tid * 4] = ((const float4*)W1f)[tid];
  if (tid < 32) *(float4*)&w2l[tid * 4] = ((const float4*)W2f)[tid];
  if (tid < 16) *(float4*)&b1l[tid * 4] = ((const float4*)b1f)[tid];
  if (tid < 2) b2l[tid] = b2f[tid];
  __syncthreads();

  int bid = blockIdx.x;
  int swz = (bid & 7) * 32 + (bid >> 3);   // bijective XCD swizzle (256 = 8*32)
  const int i0 = (swz >> 3) * 128;         // 32 i-tiles
  const int c0 = (swz & 7) * 256;          // 8 sf-tiles

  const int aOffC = wr2 * 8192 + (l & 15) * 128;
  const int bOffC = 16384 + wc2 * 8192 + (l & 15) * 128;
  const int colKK0 = (((l >> 4) * 16)) ^ ((l & 7) << 4);
  const int colKK1 = ((64 + (l >> 4) * 16)) ^ ((l & 7) << 4);

  const int srow = tid >> 3;
  const int scol = (((tid & 7) ^ (srow & 7)) << 4);
  const char* gA = (const char*)A + (size_t)(i0 + srow) * 8192 + scol;
  const char* gB = (const char*)B + (size_t)(c0 + srow) * 8192 + scol;
  char* ldsW = (char*)lds + wid * 1024;
  const char* ldsR = (const char*)lds;

  f32x4 acc[4][4];
  #pragma unroll
  for (int m = 0; m < 4; ++m)
    #pragma unroll
    for (int n = 0; n < 4; ++n) acc[m][n] = {0.f, 0.f, 0.f, 0.f};

  bf16x8 af[4][2], bfr[2][2];

#define STAGE6(K2, BOFS) do {                                                        \
    __builtin_amdgcn_global_load_lds((const AS1 void*)(gA + (K2)),                   \
        (AS3 void*)(ldsW + (BOFS)), 16, 0, 0);                                       \
    __builtin_amdgcn_global_load_lds((const AS1 void*)(gA + 524288 + (K2)),          \
        (AS3 void*)(ldsW + (BOFS) + 8192), 16, 0, 0);                                \
    __builtin_amdgcn_global_load_lds((const AS1 void*)(gB + (K2)),                   \
        (AS3 void*)(ldsW + (BOFS) + 16384), 16, 0, 0);                               \
    __builtin_amdgcn_global_load_lds((const AS1 void*)(gB + 524288 + (K2)),          \
        (AS3 void*)(ldsW + (BOFS) + 24576), 16, 0, 0);                               \
    __builtin_amdgcn_global_load_lds((const AS1 void*)(gB + 1048576 + (K2)),         \
        (AS3 void*)(ldsW + (BOFS) + 32768), 16, 0, 0);                               \
    __builtin_amdgcn_global_load_lds((const AS1 void*)(gB + 1572864 + (K2)),         \
        (AS3 void*)(ldsW + (BOFS) + 40960), 16, 0, 0);                               \
  } while (0)

#define READ_AF(BOFS) do {                                                           \
    _Pragma("unroll")                                                                \
    for (int _m = 0; _m < 4; ++_m) {                                                 \
      const char* _p = ldsR + (BOFS) + aOffC + _m * 2048;                            \
      af[_m][0] = *(const bf16x8*)(_p + colKK0);                                     \
      af[_m][1] = *(const bf16x8*)(_p + colKK1);                                     \
    } } while (0)

#define READ_B(BOFS, NH) do {                                                        \
    _Pragma("unroll")                                                                \
    for (int _j = 0; _j < 2; ++_j) {                                                 \
      const char* _p = ldsR + (BOFS) + bOffC + ((NH) * 2 + _j) * 2048;               \
      bfr[_j][0] = *(const bf16x8*)(_p + colKK0);                                    \
      bfr[_j][1] = *(const bf16x8*)(_p + colKK1);                                    \
    } } while (0)

#define MFMA_H(NH) do {                                                              \
    __builtin_amdgcn_s_setprio(1);                                                   \
    _Pragma("unroll")                                                                \
    for (int _kk = 0; _kk < 2; ++_kk)                                                \
      _Pragma("unroll")                                                              \
      for (int _m = 0; _m < 4; ++_m)                                                 \
        _Pragma("unroll")                                                            \
        for (int _j = 0; _j < 2; ++_j)                                               \
          acc[_m][(NH) * 2 + _j] = __builtin_amdgcn_mfma_f32_16x16x32_bf16(          \
              af[_m][_kk], bfr[_j][_kk], acc[_m][(NH) * 2 + _j], 0, 0, 0);           \
    __builtin_amdgcn_s_setprio(0);                                                   \
  } while (0)

  STAGE6(0, 0);
  STAGE6(128, 49152);
  VMCNT6();
  SBAR();

  int bofs = 0, bofs2 = 98304;
  for (int kt = 0; kt < 64; ++kt) {
    const int k2 = ((kt + 2) & 63) * 128;
    READ_AF(bofs);
    READ_B(bofs, 0);
    STAGE6(k2, bofs2);
    MFMA_H(0);
    READ_B(bofs, 1);
    MFMA_H(1);
    VMCNT6();
    SBAR();
    bofs = (bofs == 98304) ? 0 : bofs + 49152;
    bofs2 = (bofs2 == 98304) ? 0 : bofs2 + 49152;
  }
  VMCNT0();
  __syncthreads();   // LDS now reusable

  // ---- fused GCN output epilogue (verified in round 7) ----
  unsigned short* C1L = (unsigned short*)lds;
  {
    const int rb = wr2 * 64 + (l >> 4) * 4;
    const int cbL = wc2 * 64 + (l & 15);
    #pragma unroll
    for (int m = 0; m < 4; ++m)
      #pragma unroll
      for (int r = 0; r < 4; ++r) {
        const int row = rb + m * 16 + r;
        #pragma unroll
        for (int n = 0; n < 4; ++n)
          C1L[row * 264 + cbL + n * 16] = f2bf(acc[m][n][r]);
      }
  }
  __syncthreads();
  #pragma unroll
  for (int pp = 0; pp < 2; ++pp) {
    const int p = tid + pp * 512;
    const int s = p >> 7, il = p & 127;
    const u16x8* cp = (const u16x8*)(C1L + il * 264 + s * 32);
    float cf[32];
    #pragma unroll
    for (int q = 0; q < 4; ++q) {
      u16x8 v = cp[q];
      #pragma unroll
      for (int e = 0; e < 8; ++e) cf[q * 8 + e] = bf2f((unsigned short)v[e]);
    }
    const float rs = rowsum[i0 + il];
    const f32x4* b1v = (const f32x4*)b1l;
    f32x4 h[16];
    #pragma unroll
    for (int t = 0; t < 16; ++t) h[t] = rs * b1v[t];
    #pragma unroll
    for (int f = 0; f < 32; ++f) {
      const float c = cf[f];
      const f32x4* wrow = (const f32x4*)(w1l + f * 64);
      #pragma unroll
      for (int t = 0; t < 16; ++t) h[t] += c * wrow[t];
    }
    float o0 = b2l[0], o1 = b2l[1];
    #pragma unroll
    for (int t = 0; t < 16; ++t)
      #pragma unroll
      for (int e = 0; e < 4; ++e) {
        float a = h[t][e];
        a = a > 0.f ? a : 0.f;
        o0 += a * w2l[(t * 4 + e) * 2];
        o1 += a * w2l[(t * 4 + e) * 2 + 1];
      }
    B2t[(size_t)(((c0 >> 5) + s) * 2 + 0) * 4096 + i0 + il] = f2bf(o0);
    B2t[(size_t)(((c0 >> 5) + s) * 2 + 1) * 4096 + i0 + il] = f2bf(o1);
  }
}

// ---------------- shared MFMA GEMM core (m97-style, used by gemm2) ----------------
__device__ __forceinline__ void gemm_core(const unsigned short* __restrict__ A,
                                          const unsigned short* __restrict__ B,
                                          int i0, int c0, int k0base, int ksteps,
                                          f32x4 acc[4][4],
                                          unsigned short* Als, unsigned short* Bls) {
  const int tid = threadIdx.x;
  const int w = tid >> 6, l = tid & 63;
  const int srow = (l >> 2);
  const int scol = (l & 3) * 16;
  for (int kt = 0; kt < ksteps; ++kt) {
    int k0 = k0base + kt * 32;
    #pragma unroll
    for (int q = 0; q < 2; ++q) {
      int r = w * 32 + q * 16 + srow;
      const char* ga = (const char*)(A + (size_t)(i0 + r) * 4096 + k0) + scol;
      __builtin_amdgcn_global_load_lds(
          (const AS1 void*)ga,
          (AS3 void*)((char*)Als + w * 2048 + q * 1024), 16, 0, 0);
      const char* gb = (const char*)(B + (size_t)(c0 + r) * 4096 + k0) + scol;
      __builtin_amdgcn_global_load_lds(
          (const AS1 void*)gb,
          (AS3 void*)((char*)Bls + w * 2048 + q * 1024), 16, 0, 0);
    }
    __syncthreads();
    const int wr = w >> 1, wc = w & 1;
    bf16x8 af[4], bff[4];
    #pragma unroll
    for (int m = 0; m < 4; ++m)
      af[m] = *(const bf16x8*)(Als + (wr * 64 + m * 16 + (l & 15)) * 32 + (l >> 4) * 8);
    #pragma unroll
    for (int n = 0; n < 4; ++n)
      bff[n] = *(const bf16x8*)(Bls + (wc * 64 + n * 16 + (l & 15)) * 32 + (l >> 4) * 8);
    #pragma unroll
    for (int m = 0; m < 4; ++m)
      #pragma unroll
      for (int n = 0; n < 4; ++n)
        acc[m][n] = __builtin_amdgcn_mfma_f32_16x16x32_bf16(af[m], bff[n], acc[m][n], 0, 0, 0);
    __syncthreads();
  }
}

// ---------------- GEMM2 split-K: Gp[ks][i][c2] partial f32 ----------------
__global__ __launch_bounds__(256) void k_gemm2(const unsigned short* __restrict__ A,
                                               const unsigned short* __restrict__ B,
                                               float* __restrict__ Gp) {
  __shared__ unsigned short Als[128 * 32], Bls[128 * 32];
  int id = blockIdx.x;
  int bi = id & 31, ks = id >> 5;
  int i0 = bi * 128;
  f32x4 acc[4][4];
  #pragma unroll
  for (int m = 0; m < 4; ++m)
    #pragma unroll
    for (int n = 0; n < 4; ++n) acc[m][n] = {0.f, 0.f, 0.f, 0.f};
  gemm_core(A, B, i0, 0, ks * 512, 16, acc, Als, Bls);
  float* outp = Gp + (size_t)ks * 4096 * 128;
  int l = threadIdx.x & 63, w = threadIdx.x >> 6;
  int wr = w >> 1, wc = w & 1;
  int rbase = i0 + wr * 64 + (l >> 4) * 4;
  int cbase = wc * 64 + (l & 15);
  #pragma unroll
  for (int m = 0; m < 4; ++m)
    #pragma unroll
    for (int n = 0; n < 4; ++n)
      #pragma unroll
      for (int r = 0; r < 4; ++r)
        outp[(size_t)(rbase + m * 16 + r) * 128 + cbase + n * 16] = acc[m][n][r];
}

// ---------------- reduce split-K + log_softmax -> R[s][i*2+o] f32 ----------------
__global__ __launch_bounds__(256) void k_lsm(const float* __restrict__ Gp,
                                             float* __restrict__ Rm) {
  __shared__ float Gacc[32][130];
  int i0 = blockIdx.x * 32;
  int tid = threadIdx.x;
  float4 v[4];
  #pragma unroll
  for (int i = 0; i < 4; ++i) v[i] = {0.f, 0.f, 0.f, 0.f};
  for (int ks = 0; ks < 8; ++ks) {
    const float4* gp4 = ((const float4*)Gp) + (size_t)ks * 131072 + (size_t)i0 * 32;
    #pragma unroll
    for (int i = 0; i < 4; ++i) {
      float4 t = gp4[tid + i * 256];
      v[i].x += t.x; v[i].y += t.y; v[i].z += t.z; v[i].w += t.w;
    }
  }
  #pragma unroll
  for (int i = 0; i < 4; ++i) {
    int f4i = tid + i * 256, row = f4i >> 5, c = (f4i & 31) * 4;
    Gacc[row][c] = v[i].x; Gacc[row][c + 1] = v[i].y;
    Gacc[row][c + 2] = v[i].z; Gacc[row][c + 3] = v[i].w;
  }
  __syncthreads();
  #pragma unroll
  for (int j = 0; j < 8; ++j) {
    int p = j * 256 + tid;
    int ii = p & 31, s = p >> 5;
    float g0 = Gacc[ii][s * 2], g1 = Gacc[ii][s * 2 + 1];
    float m = fmaxf(g0, g1);
    float lse = m + logf(expf(g0 - m) + expf(g1 - m));
    float2 o_; o_.x = g0 - lse; o_.y = g1 - lse;
    *((float2*)(Rm + (size_t)s * 8192 + (size_t)(i0 + ii) * 2)) = o_;
  }
}

// ---------------- gi0 partial: part[ks][t][g] = R[t] . Wih0[g] over c-range ----------------
__global__ __launch_bounds__(256) void k_gi0(const float* __restrict__ Rm,
                                             const float* __restrict__ Wih0,
                                             float* __restrict__ part) {
  __shared__ float4 Wl[4 * 128];
  int gb = blockIdx.x % 48, ks = blockIdx.x / 48;
  int c0 = ks * 512;
  int tid = threadIdx.x;
  #pragma unroll
  for (int i = 0; i < 2; ++i) {
    int idx = tid + i * 256;
    int g = idx >> 7, c4 = idx & 127;
    Wl[g * 128 + c4] = ((const float4*)(Wih0 + (size_t)(gb * 4 + g) * 8192 + c0))[c4];
  }
  __syncthreads();
  int w = tid >> 6, lane = tid & 63;
  for (int pass = 0; pass < 16; ++pass) {
    int t = pass * 4 + w;
    float a0 = 0.f, a1 = 0.f, a2 = 0.f, a3 = 0.f;
    const float4* rg = (const float4*)(Rm + (size_t)t * 8192 + c0);
    #pragma unroll
    for (int i = 0; i < 2; ++i) {
      int c4 = i * 64 + lane;
      float4 r4 = rg[c4];
      float4 w0 = Wl[c4], w1 = Wl[128 + c4], w2 = Wl[256 + c4], w3 = Wl[384 + c4];
      a0 += r4.x * w0.x + r4.y * w0.y + r4.z * w0.z + r4.w * w0.w;
      a1 += r4.x * w1.x + r4.y * w1.y + r4.z * w1.z + r4.w * w1.w;
      a2 += r4.x * w2.x + r4.y * w2.y + r4.z * w2.z + r4.w * w2.w;
      a3 += r4.x * w3.x + r4.y * w3.y + r4.z * w3.z + r4.w * w3.w;
    }
    #pragma unroll
    for (int off = 1; off < 64; off <<= 1) {
      a0 += __shfl_xor(a0, off);
      a1 += __shfl_xor(a1, off);
      a2 += __shfl_xor(a2, off);
      a3 += __shfl_xor(a3, off);
    }
    if (lane == 0) {
      float4 o_; o_.x = a0; o_.y = a1; o_.z = a2; o_.w = a3;
      *((float4*)(part + ((size_t)ks * 64 + t) * 192 + gb * 4)) = o_;
    }
  }
}

__global__ __launch_bounds__(256) void k_gi0red(const float* __restrict__ part,
                                                const float* __restrict__ bih0,
                                                float* __restrict__ gi0) {
  int idx = blockIdx.x * 256 + threadIdx.x;
  if (idx < 12288) {
    float s_ = bih0[idx % 192];
    for (int ks = 0; ks < 16; ++ks) s_ += part[ks * 12288 + idx];
    gi0[idx] = s_;
  }
}

// =====================================================================
// MFMA GRU (unchanged — proven round 6)
// =====================================================================
__device__ __forceinline__ float fsigm(float x) {
  return __builtin_amdgcn_rcpf(1.f + __expf(-x));
}
__device__ __forceinline__ float ftanh(float x) {
  return 1.f - 2.f * __builtin_amdgcn_rcpf(1.f + __expf(2.f * x));
}

__global__ __launch_bounds__(384) void k_gru(const float* __restrict__ gi0,
                                             const float* __restrict__ Whh0,
                                             const float* __restrict__ bhh0,
                                             const float* __restrict__ Wih1,
                                             const float* __restrict__ Whh1,
                                             const float* __restrict__ bih1,
                                             const float* __restrict__ bhh1,
                                             float* __restrict__ out) {
  __shared__ float gil[64][192];
  __shared__ float gout[576];
  __shared__ __align__(16) unsigned short hv[2][64];
  const int tid = threadIdx.x;
  const int w = tid >> 6, l = tid & 63;
  const int matw = w >> 1, half = w & 1;
  const float* Wm = (matw == 0) ? Whh0 : (matw == 1 ? Wih1 : Whh1);
  const int mi = (matw == 2) ? 1 : 0;

  bf16x8 afr[6][2];
  #pragma unroll
  for (int rbi = 0; rbi < 6; ++rbi) {
    int g = (half * 6 + rbi) * 16 + (l & 15);
    #pragma unroll
    for (int kh = 0; kh < 2; ++kh) {
      int k0 = kh * 32 + (l >> 4) * 8;
      const float4* src = (const float4*)(Wm + (size_t)g * 64 + k0);
      float4 v0 = src[0], v1 = src[1];
      bf16x8 a;
      a[0] = (short)f2bf(v0.x); a[1] = (short)f2bf(v0.y);
      a[2] = (short)f2bf(v0.z); a[3] = (short)f2bf(v0.w);
      a[4] = (short)f2bf(v1.x); a[5] = (short)f2bf(v1.y);
      a[6] = (short)f2bf(v1.z); a[7] = (short)f2bf(v1.w);
      afr[rbi][kh] = a;
    }
  }
  {
    float4* gf = (float4*)&gil[0][0];
    const float4* gs = (const float4*)gi0;
    #pragma unroll
    for (int i = 0; i < 8; ++i) gf[i * 384 + tid] = gs[i * 384 + tid];
  }
  if (tid < 128) hv[tid >> 6][tid & 63] = 0;

  float hreg = 0.f;
  float bR = 0.f, bZ = 0.f, bNa = 0.f, bNb = 0.f;
  if (tid < 64) {
    bR = bhh0[tid]; bZ = bhh0[64 + tid]; bNa = bhh0[128 + tid];
  } else if (tid < 128) {
    int g = tid - 64;
    bR = bih1[g] + bhh1[g];
    bZ = bih1[64 + g] + bhh1[64 + g];
    bNa = bih1[128 + g];
    bNb = bhh1[128 + g];
  }
  asm volatile("s_waitcnt lgkmcnt(0)\n\ts_barrier" ::: "memory");

  const int gwb = matw * 192 + half * 96 + (l >> 4) * 4;
  const f32x4 zacc = {0.f, 0.f, 0.f, 0.f};

  for (int i = 0; i <= 64; ++i) {
    bf16x8 b0 = *(const bf16x8*)&hv[mi][(l >> 4) * 8];
    bf16x8 b1 = *(const bf16x8*)&hv[mi][32 + (l >> 4) * 8];
    #pragma unroll
    for (int rbi = 0; rbi < 6; ++rbi) {
      f32x4 a_ = __builtin_amdgcn_mfma_f32_16x16x32_bf16(afr[rbi][0], b0, zacc, 0, 0, 0);
      a_ = __builtin_amdgcn_mfma_f32_16x16x32_bf16(afr[rbi][1], b1, a_, 0, 0, 0);
      if (!(l & 15)) *(f32x4*)&gout[gwb + rbi * 16] = a_;
    }
    asm volatile("s_waitcnt lgkmcnt(0)\n\ts_barrier" ::: "memory");
    if (tid < 64) {
      if (i < 64) {
        float r = fsigm(gil[i][tid] + gout[tid] + bR);
        float z = fsigm(gil[i][64 + tid] + gout[64 + tid] + bZ);
        float n = ftanh(gil[i][128 + tid] + r * (gout[128 + tid] + bNa));
        hreg = (1.f - z) * n + z * hreg;
        hv[0][tid] = f2bf(hreg);
      }
    } else if (tid < 128 && i > 0) {
      int g = tid - 64;
      float r = fsigm(gout[192 + g] + gout[384 + g] + bR);
      float z = fsigm(gout[256 + g] + gout[448 + g] + bZ);
      float n = ftanh((gout[320 + g] + bNa) + r * (gout[512 + g] + bNb));
      hreg = (1.f - z) * n + z * hreg;
      hv[1][g] = f2bf(hreg);
      out[(i - 1) * 64 + g] = hreg;
    }
    asm volatile("s_waitcnt lgkmcnt(0)\n\ts_barrier" ::: "memory");
  }
  if (tid < 64) out[4096 + tid] = hreg;
  else if (tid < 128) out[4096 + 64 + (tid - 64)] = hreg;
}

extern "C" void kernel_launch(void* const* d_in, const int* in_sizes, int n_in,
                              void* d_out, int out_size, void* d_ws, size_t ws_size,
                              hipStream_t stream) {
  const float* x    = (const float*)d_in[0];
  const float* adj  = (const float*)d_in[1];
  const float* W1   = (const float*)d_in[2];
  const float* b1   = (const float*)d_in[3];
  const float* W2   = (const float*)d_in[4];
  const float* b2   = (const float*)d_in[5];
  const float* Wih0 = (const float*)d_in[6];
  const float* Whh0 = (const float*)d_in[7];
  const float* bih0 = (const float*)d_in[8];
  const float* bhh0 = (const float*)d_in[9];
  const float* Wih1 = (const float*)d_in[10];
  const float* Whh1 = (const float*)d_in[11];
  const float* bih1 = (const float*)d_in[12];
  const float* bhh1 = (const float*)d_in[13];
  float* out = (float*)d_out;

  char* ws = (char*)d_ws;
  unsigned short* adjb = (unsigned short*)ws;                      // 33.55MB
  unsigned short* Xt   = (unsigned short*)(ws + 33554432);         // 16.78MB
  float* rowsum        = (float*)(ws + 67108864);                  // 16KB
  float* Gp            = (float*)(ws + 67125248);                  // 16.78MB
  float* Rm            = (float*)(ws + 83902464);                  // 2MB
  float* part          = (float*)(ws + 85999616);                  // 768KB
  float* gi0           = (float*)(ws + 86786048);                  // 48KB
  unsigned short* B2t  = (unsigned short*)(ws + 86835200);         // 1MB

  k_prep<<<8192, 256, 0, stream>>>(adj, adjb, rowsum, x, Xt);
  k_gemmAX<<<256, 512, 0, stream>>>(adjb, Xt, rowsum, W1, b1, W2, b2, B2t);
  k_gemm2<<<256, 256, 0, stream>>>(adjb, B2t, Gp);
  k_lsm<<<128, 256, 0, stream>>>(Gp, Rm);
  k_gi0<<<768, 256, 0, stream>>>(Rm, Wih0, part);
  k_gi0red<<<48, 256, 0, stream>>>(part, bih0, gi0);
  k_gru<<<1, 384, 0, stream>>>(gi0, Whh0, bhh0, Wih1, Whh1, bih1, bhh1, out);
}